// Round 14
// baseline (456.509 us; speedup 1.0000x reference)
//
#include <hip/hip_runtime.h>
#include <cstdint>
#include <cstddef>

#define BETA 5.5f
#define ALPHA 0.5f

constexpr int D   = 512;     // feature dim
constexpr int NB  = 4096;    // queries
constexpr int NK  = 16384;   // keys
constexpr int BQ  = 32;      // query tile per block
constexpr int BN  = 128;     // key chunk (2 barriers per 128 keys = R10's rate)
constexpr int NSPLIT = 8;    // nsplit = blockIdx&7 ~ XCD id -> 4MB L2 slice
constexpr int NRANGE = NK / NSPLIT;   // 2048
constexpr int CHUNKS = NRANGE / BN;   // 16
constexpr int KROW = D + 8;           // padded K row: 520 elems, 1040 B
constexpr int PROW = BN + 8;          // padded P row: 136

typedef __attribute__((ext_vector_type(8)))  short    short8;
typedef __attribute__((ext_vector_type(4)))  float    floatx4;
typedef __attribute__((ext_vector_type(16))) float    floatx16;
typedef __attribute__((ext_vector_type(4)))  uint32_t uint4v;
typedef __attribute__((ext_vector_type(2)))  uint32_t uint2v;

__device__ inline uint32_t f2bf1(float f) {
  union { float f; uint32_t u; } v; v.f = f;
  return (v.u + 0x7FFFu + ((v.u >> 16) & 1u)) >> 16;   // RNE
}
__device__ inline uint32_t pack2(float a, float b) {
  return f2bf1(a) | (f2bf1(b) << 16);
}
__device__ inline float bflo(uint32_t u) {
  union { uint32_t u; float f; } v; v.u = u << 16; return v.f;
}
__device__ inline float bfhi(uint32_t u) {
  union { uint32_t u; float f; } v; v.u = u & 0xFFFF0000u; return v.f;
}

__device__ inline void load_lds16(const void* g, void* l) {
  __builtin_amdgcn_global_load_lds(
      (const __attribute__((address_space(1))) uint32_t*)g,
      (__attribute__((address_space(3))) uint32_t*)l, 16, 0, 0);
}

// ---- merged: blocks 0..255 normalize K -> Kn + KnT; 256.. normalize Q ------
__global__ void norm_qk_kernel(const float* __restrict__ q,
                               const float* __restrict__ k,
                               float* __restrict__ out,
                               unsigned short* __restrict__ Qn,
                               unsigned short* __restrict__ Kn,
                               unsigned short* __restrict__ KnT) {
  __shared__ unsigned short tile[64 * KROW];
  const int wave = threadIdx.x >> 6, lane = threadIdx.x & 63;

  if (blockIdx.x >= 256) {               // ---- Q path ----
    const int row = (blockIdx.x - 256) * 4 + wave;
    const float4* qr = (const float4*)(q + (size_t)row * D);
    float4 a = qr[lane * 2];
    float4 b = qr[lane * 2 + 1];
    float ss = a.x*a.x + a.y*a.y + a.z*a.z + a.w*a.w
             + b.x*b.x + b.y*b.y + b.z*b.z + b.w*b.w;
#pragma unroll
    for (int m = 32; m >= 1; m >>= 1) ss += __shfl_xor(ss, m, 64);
    const float sc = 1.0f / fmaxf(sqrtf(ss), 1e-12f);
    float4* orow = (float4*)(out + (size_t)row * D);
    orow[lane * 2]     = a;
    orow[lane * 2 + 1] = b;
    uint4v w;
    w.x = pack2(a.x*sc, a.y*sc); w.y = pack2(a.z*sc, a.w*sc);
    w.z = pack2(b.x*sc, b.y*sc); w.w = pack2(b.z*sc, b.w*sc);
    *(uint4v*)(Qn + (size_t)row * D + lane * 8) = w;
    return;
  }
  // ---- K path ----
  const int n0 = blockIdx.x * 64;
#pragma unroll 1
  for (int i = 0; i < 16; ++i) {
    const int rl = wave * 16 + i;
    const int n  = n0 + rl;
    const float4* kr = (const float4*)(k + (size_t)n * D);
    float4 a = kr[lane * 2], b = kr[lane * 2 + 1];
    float ss = a.x*a.x + a.y*a.y + a.z*a.z + a.w*a.w
             + b.x*b.x + b.y*b.y + b.z*b.z + b.w*b.w;
#pragma unroll
    for (int m = 32; m >= 1; m >>= 1) ss += __shfl_xor(ss, m, 64);
    const float sc = 1.0f / fmaxf(sqrtf(ss), 1e-12f);
    uint4v w;
    w.x = pack2(a.x*sc, a.y*sc); w.y = pack2(a.z*sc, a.w*sc);
    w.z = pack2(b.x*sc, b.y*sc); w.w = pack2(b.z*sc, b.w*sc);
    *(uint4v*)(Kn + (size_t)n * D + lane * 8) = w;
    *(uint4v*)&tile[rl * KROW + lane * 8]     = w;
  }
  __syncthreads();
  const int dsub = threadIdx.x >> 3;        // 0..31
  const int nl   = (threadIdx.x & 7) * 8;   // 0..56
#pragma unroll 1
  for (int iter = 0; iter < 16; ++iter) {
    const int d = iter * 32 + dsub;
    uint4v w;
    w.x = (uint32_t)tile[(nl+0)*KROW + d] | ((uint32_t)tile[(nl+1)*KROW + d] << 16);
    w.y = (uint32_t)tile[(nl+2)*KROW + d] | ((uint32_t)tile[(nl+3)*KROW + d] << 16);
    w.z = (uint32_t)tile[(nl+4)*KROW + d] | ((uint32_t)tile[(nl+5)*KROW + d] << 16);
    w.w = (uint32_t)tile[(nl+6)*KROW + d] | ((uint32_t)tile[(nl+7)*KROW + d] << 16);
    *(uint4v*)(KnT + (size_t)d * NK + n0 + nl) = w;
  }
}

// ---------------- fused: S = Qn Kn^T chunk, P = exp, O += P Kn --------------
// BN=128, 32x32x16 GEMM1 kh-split. NO Sred array: kh=1 waves write bf16
// partial S directly into P_lds; kh=0 waves read-add-exp-rewrite after barA.
// K single-buffered (stage after barA, drained at barB behind GEMM2+exp).
// GEMM2 lags one chunk (P(c) consumed in region B(c+1)). 2 barriers / 128
// keys == R10's barrier rate with ~half the LDS traffic and faster MFMA.
__global__ __launch_bounds__(512, 2) void fused_kernel(
    const unsigned short* __restrict__ Qn,
    const unsigned short* __restrict__ Kn,
    const unsigned short* __restrict__ KnT,
    float* __restrict__ out) {
  __shared__ unsigned short K_lds[BN * KROW];      // 133120 B
  __shared__ unsigned short P_lds[2][BQ * PROW];   //  17408 B  (150.5 KB)

  const int tid  = threadIdx.x;
  const int wave = tid >> 6, lane = tid & 63;
  const int l15  = lane & 15, quad = lane >> 4;
  const int l31  = lane & 31, half = lane >> 5;
  const int nsplit = blockIdx.x & (NSPLIT - 1);
  const int qidx   = blockIdx.x >> 3;           // 0..127
  const int q0     = qidx * BQ;
  const int nbase  = nsplit * NRANGE;
  const int nt = wave & 3, kh = wave >> 2;      // GEMM1: n-32-tile, D-half
  const int dbase = wave * 64;                  // GEMM2: wave's 64 d-cols

  // GEMM1 B-frags (Q, 32q, this kh D-half): 64 VGPR  [R12-verified layout]
  short8 qfB[16];
  {
    const unsigned short* qrow = Qn + (size_t)(q0 + l31) * D + kh * 256 + half * 8;
#pragma unroll
    for (int ks = 0; ks < 16; ++ks) qfB[ks] = *(const short8*)(qrow + ks * 16);
  }

  floatx4 oacc[2][4] = {};   // 32q x 64d O slice: 32 AGPR
  short8 ktf[4][4];          // GEMM2 B-frags for full k=128: 64 VGPR

  auto stage = [&](int ch) {
#pragma unroll
    for (int i = 0; i < 16; ++i) {
      const int row = wave * 16 + i;
      load_lds16(Kn + (size_t)(nbase + ch*BN + row) * D + lane * 8,
                 &K_lds[row * KROW]);
    }
  };
  auto ktf_load = [&](int ch) {
#pragma unroll
    for (int kb2 = 0; kb2 < 4; ++kb2)
#pragma unroll
      for (int td = 0; td < 4; ++td)
        ktf[kb2][td] = *(const short8*)(KnT + (size_t)(dbase + td*16 + l15) * NK
                                        + (nbase + ch*BN + kb2*32 + quad*8));
  };
  auto gemm1 = [&](floatx16& s) {
    const unsigned short* abase = &K_lds[(nt*32 + l31) * KROW + kh*256 + half*8];
#pragma unroll
    for (int ks = 0; ks < 16; ++ks) {
      short8 a = *(const short8*)(abase + ks * 16);
      s = __builtin_amdgcn_mfma_f32_32x32x16_bf16(a, qfB[ks], s, 0, 0, 0);
    }
  };
  // kh=1: write bf16 partial S into P buffer (same indexing as exp path)
  auto partial_write = [&](int buf, const floatx16& s) {
#pragma unroll
    for (int g = 0; g < 4; ++g) {
      uint2v w; w.x = pack2(s[4*g+0], s[4*g+1]); w.y = pack2(s[4*g+2], s[4*g+3]);
      *(uint2v*)&P_lds[buf][l31 * PROW + nt*32 + g*8 + half*4] = w;
    }
  };
  // kh=0: read partial, add own, exp, repack, write final
  auto finalize = [&](int buf, const floatx16& s) {
#pragma unroll
    for (int g = 0; g < 4; ++g) {
      uint2v* addr = (uint2v*)&P_lds[buf][l31 * PROW + nt*32 + g*8 + half*4];
      uint2v r = *addr;
      float e0 = __expf(BETA * (s[4*g+0] + bflo(r.x) - 1.f));
      float e1 = __expf(BETA * (s[4*g+1] + bfhi(r.x) - 1.f));
      float e2 = __expf(BETA * (s[4*g+2] + bflo(r.y) - 1.f));
      float e3 = __expf(BETA * (s[4*g+3] + bfhi(r.y) - 1.f));
      uint2v w; w.x = pack2(e0, e1); w.y = pack2(e2, e3);
      *addr = w;
    }
  };
  auto gemm2 = [&](int buf) {
#pragma unroll
    for (int kb2 = 0; kb2 < 4; ++kb2) {
#pragma unroll
      for (int tr = 0; tr < 2; ++tr) {
        short8 pf = *(const short8*)&P_lds[buf][(tr*16 + l15) * PROW
                                               + kb2*32 + quad*8];
#pragma unroll
        for (int td = 0; td < 4; ++td)
          oacc[tr][td] = __builtin_amdgcn_mfma_f32_16x16x32_bf16(
              pf, ktf[kb2][td], oacc[tr][td], 0, 0, 0);
      }
    }
  };

  // ---- prologue: chunk 0
  stage(0);
  __syncthreads();                       // staging(0) drained
  {
    floatx16 s = {};
    gemm1(s);
    if (kh == 1) partial_write(0, s);
    __syncthreads();                     // barA(0): K reads done; partial visible
    stage(1);
    if (kh == 0) finalize(0, s);
    ktf_load(0);
    __syncthreads();                     // barB(0): P(0) visible; staging(1) drained
  }

  // ---- steady: iter c = regionA{GEMM1(c), partial} barA
  //              regionB{stage(c+1), GEMM2(c-1), finalize(c), ktf(c)} barB
#pragma unroll 1
  for (int c = 1; c < CHUNKS; ++c) {
    floatx16 s = {};
    gemm1(s);                            // reads K_lds = chunk c
    if (kh == 1) partial_write(c & 1, s);
    __syncthreads();                     // barA(c)
    if (c + 1 < CHUNKS) stage(c + 1);    // WAR-safe: K reads done at barA
    gemm2((c - 1) & 1);                  // P(c-1) + ktf(c-1)
    if (kh == 0) finalize(c & 1, s);
    ktf_load(c);                         // consumed next region (2 barriers away)
    __syncthreads();                     // barB(c): P(c) visible; staging drained
  }
  gemm2((CHUNKS - 1) & 1);               // tail: GEMM2(last)

  // ---- epilogue: out += ALPHA * O (out pre-init to Q; atomics L2-coalesce)
#pragma unroll
  for (int tr = 0; tr < 2; ++tr)
#pragma unroll
    for (int td = 0; td < 4; ++td)
#pragma unroll
      for (int r = 0; r < 4; ++r)
        atomicAdd(out + (size_t)(q0 + tr*16 + quad*4 + r) * D
                      + dbase + td*16 + l15,
                  ALPHA * oacc[tr][td][r]);
}

extern "C" void kernel_launch(void* const* d_in, const int* in_sizes, int n_in,
                              void* d_out, int out_size, void* d_ws, size_t ws_size,
                              hipStream_t stream) {
  (void)in_sizes; (void)n_in; (void)out_size; (void)ws_size;
  const float* q = (const float*)d_in[0];
  const float* k = (const float*)d_in[1];
  float* out = (float*)d_out;
  unsigned short* Qn  = (unsigned short*)d_ws;          //  4 MB
  unsigned short* Kn  = Qn + (size_t)NB * D;            // 16 MB
  unsigned short* KnT = Kn + (size_t)NK * D;            // 16 MB  (total 36 MB)

  hipLaunchKernelGGL(norm_qk_kernel, dim3(256 + NB / 4), dim3(256), 0, stream,
                     q, k, out, Qn, Kn, KnT);
  hipLaunchKernelGGL(fused_kernel, dim3((NB / BQ) * NSPLIT), dim3(512), 0, stream,
                     Qn, Kn, KnT, out);
}

// Round 15
// 340.088 us; speedup vs baseline: 1.3423x; 1.3423x over previous
//
#include <hip/hip_runtime.h>
#include <cstdint>
#include <cstddef>

#define BETA 5.5f
#define ALPHA 0.5f

constexpr int D   = 512;     // feature dim
constexpr int NB  = 4096;    // queries
constexpr int NK  = 16384;   // keys
constexpr int BQ  = 64;      // query tile per block
constexpr int BN  = 64;      // key chunk
constexpr int NSPLIT = 8;    // per-XCD K working set = Kn 2MB + KnT 2MB = 4MB = L2
constexpr int NRANGE = NK / NSPLIT;   // 2048
constexpr int CHUNKS = NRANGE / BN;   // 32
constexpr int KROW = D + 8;           // padded LDS row (bf16), 1040 B
constexpr int PROW = BN + 8;          // padded P row: 72

typedef __attribute__((ext_vector_type(8)))  short    short8;
typedef __attribute__((ext_vector_type(4)))  float    floatx4;
typedef __attribute__((ext_vector_type(4)))  uint32_t uint4v;
typedef __attribute__((ext_vector_type(2)))  uint32_t uint2v;

__device__ inline uint32_t f2bf1(float f) {
  union { float f; uint32_t u; } v; v.f = f;
  return (v.u + 0x7FFFu + ((v.u >> 16) & 1u)) >> 16;   // RNE
}
__device__ inline uint32_t pack2(float a, float b) {
  return f2bf1(a) | (f2bf1(b) << 16);
}

__device__ inline void load_lds16(const void* g, void* l) {
  __builtin_amdgcn_global_load_lds(
      (const __attribute__((address_space(1))) uint32_t*)g,
      (__attribute__((address_space(3))) uint32_t*)l, 16, 0, 0);
}

// ---- merged: blocks 0..255 normalize K -> Kn + KnT; 256.. normalize Q ------
__global__ void norm_qk_kernel(const float* __restrict__ q,
                               const float* __restrict__ k,
                               float* __restrict__ out,
                               unsigned short* __restrict__ Qn,
                               unsigned short* __restrict__ Kn,
                               unsigned short* __restrict__ KnT) {
  __shared__ unsigned short tile[64 * KROW];
  const int wave = threadIdx.x >> 6, lane = threadIdx.x & 63;

  if (blockIdx.x >= 256) {               // ---- Q path ----
    const int row = (blockIdx.x - 256) * 4 + wave;
    const float4* qr = (const float4*)(q + (size_t)row * D);
    float4 a = qr[lane * 2];
    float4 b = qr[lane * 2 + 1];
    float ss = a.x*a.x + a.y*a.y + a.z*a.z + a.w*a.w
             + b.x*b.x + b.y*b.y + b.z*b.z + b.w*b.w;
#pragma unroll
    for (int m = 32; m >= 1; m >>= 1) ss += __shfl_xor(ss, m, 64);
    const float sc = 1.0f / fmaxf(sqrtf(ss), 1e-12f);
    float4* orow = (float4*)(out + (size_t)row * D);
    orow[lane * 2]     = a;
    orow[lane * 2 + 1] = b;
    uint4v w;
    w.x = pack2(a.x*sc, a.y*sc); w.y = pack2(a.z*sc, a.w*sc);
    w.z = pack2(b.x*sc, b.y*sc); w.w = pack2(b.z*sc, b.w*sc);
    *(uint4v*)(Qn + (size_t)row * D + lane * 8) = w;
    return;
  }
  // ---- K path ----
  const int n0 = blockIdx.x * 64;
#pragma unroll 1
  for (int i = 0; i < 16; ++i) {
    const int rl = wave * 16 + i;
    const int n  = n0 + rl;
    const float4* kr = (const float4*)(k + (size_t)n * D);
    float4 a = kr[lane * 2], b = kr[lane * 2 + 1];
    float ss = a.x*a.x + a.y*a.y + a.z*a.z + a.w*a.w
             + b.x*b.x + b.y*b.y + b.z*b.z + b.w*b.w;
#pragma unroll
    for (int m = 32; m >= 1; m >>= 1) ss += __shfl_xor(ss, m, 64);
    const float sc = 1.0f / fmaxf(sqrtf(ss), 1e-12f);
    uint4v w;
    w.x = pack2(a.x*sc, a.y*sc); w.y = pack2(a.z*sc, a.w*sc);
    w.z = pack2(b.x*sc, b.y*sc); w.w = pack2(b.z*sc, b.w*sc);
    *(uint4v*)(Kn + (size_t)n * D + lane * 8) = w;
    *(uint4v*)&tile[rl * KROW + lane * 8]     = w;
  }
  __syncthreads();
  const int dsub = threadIdx.x >> 3;        // 0..31
  const int nl   = (threadIdx.x & 7) * 8;   // 0..56
#pragma unroll 1
  for (int iter = 0; iter < 16; ++iter) {
    const int d = iter * 32 + dsub;
    uint4v w;
    w.x = (uint32_t)tile[(nl+0)*KROW + d] | ((uint32_t)tile[(nl+1)*KROW + d] << 16);
    w.y = (uint32_t)tile[(nl+2)*KROW + d] | ((uint32_t)tile[(nl+3)*KROW + d] << 16);
    w.z = (uint32_t)tile[(nl+4)*KROW + d] | ((uint32_t)tile[(nl+5)*KROW + d] << 16);
    w.w = (uint32_t)tile[(nl+6)*KROW + d] | ((uint32_t)tile[(nl+7)*KROW + d] << 16);
    *(uint4v*)(KnT + (size_t)d * NK + n0 + nl) = w;
  }
}

// ---------------- fused: S = Qn Kn^T chunk, P = exp, O += P Kn --------------
// R10's verified cross-barrier pipeline with two targeted fixes:
//  (1) NSPLIT=8: all 32 blocks on an XCD share ONE 4MB K-slice -> L2-resident,
//      eliminating the invisible L2-miss (L3) re-stream that our counters
//      can't see (FETCH counts HBM only).
//  (2) ktf_load hoisted before the last gemm1_half: ~500 cyc of cover before
//      the barrier's vmcnt(0) drain (was ~150 -> full L2 latency exposed).
__global__ __launch_bounds__(512, 2) void fused_kernel(
    const unsigned short* __restrict__ Qn,
    const unsigned short* __restrict__ Kn,
    const unsigned short* __restrict__ KnT,
    float* __restrict__ out) {
  __shared__ unsigned short K_lds[2][BN * KROW];   // 2 x 66.5 KB
  __shared__ unsigned short P_lds[2][BQ * PROW];   // 2 x 9.2 KB  (151.5 KB)

  const int tid  = threadIdx.x;
  const int wave = tid >> 6, lane = tid & 63;
  const int l15  = lane & 15, quad = lane >> 4;
  const int nsplit = blockIdx.x & (NSPLIT - 1);   // == XCD id (round-robin)
  const int qtile  = blockIdx.x >> 3;             // 0..63
  const int q0     = qtile * BQ;
  const int nbase  = nsplit * NRANGE;
  const int tb = wave & 3, nh = wave >> 2;

  // Q B-fragments in registers: wave's 16-col b-tile, all 512 d (64 VGPR)
  short8 qf[16];
  {
    const unsigned short* qrow = Qn + (size_t)(q0 + tb * 16 + l15) * D + quad * 8;
#pragma unroll
    for (int kb = 0; kb < 16; ++kb) qf[kb] = *(const short8*)(qrow + kb * 32);
  }

  floatx4 oacc[4][4] = {};   // wave's 64x64 O slice
  short8 ktf[2][4];          // KnT B-frags (32 VGPR), single-buffered

  const unsigned short* ktrow = KnT + (size_t)(wave*64 + l15) * NK + nbase + quad*8;

  auto stage = [&](int ch, int buf) {
#pragma unroll
    for (int i = 0; i < 8; ++i) {
      const int row = wave * 8 + i;
      load_lds16(Kn + (size_t)(nbase + ch*BN + row) * D + lane * 8,
                 &K_lds[buf][row * KROW]);
    }
  };
  auto gemm1_half = [&](int buf, int kb0, floatx4& s0, floatx4& s1) {
#pragma unroll
    for (int kb = kb0; kb < kb0 + 8; ++kb) {
      short8 a0 = *(const short8*)&K_lds[buf][(nh*32 +      l15) * KROW + kb*32 + quad*8];
      short8 a1 = *(const short8*)&K_lds[buf][(nh*32 + 16 + l15) * KROW + kb*32 + quad*8];
      s0 = __builtin_amdgcn_mfma_f32_16x16x32_bf16(a0, qf[kb], s0, 0, 0, 0);
      s1 = __builtin_amdgcn_mfma_f32_16x16x32_bf16(a1, qf[kb], s1, 0, 0, 0);
    }
  };
  auto gemm2_half = [&](int buf, int kb2) {
    short8 pf[4];
#pragma unroll
    for (int tr = 0; tr < 4; ++tr)
      pf[tr] = *(const short8*)&P_lds[buf][(tr*16 + l15) * PROW + kb2*32 + quad*8];
#pragma unroll
    for (int td = 0; td < 4; ++td)
#pragma unroll
      for (int tr = 0; tr < 4; ++tr)
        oacc[tr][td] = __builtin_amdgcn_mfma_f32_16x16x32_bf16(
            pf[tr], ktf[kb2][td], oacc[tr][td], 0, 0, 0);
  };
  auto ktf_load = [&](int ch) {
#pragma unroll
    for (int kb2 = 0; kb2 < 2; ++kb2)
#pragma unroll
      for (int td = 0; td < 4; ++td)
        ktf[kb2][td] = *(const short8*)(ktrow + (size_t)td*16*NK + ch*BN + kb2*32);
  };
  auto exp_pw = [&](int buf, const floatx4& s0, const floatx4& s1) {
    const int prow = (tb * 16 + l15) * PROW;
    uint2v w0, w1;
    w0.x = pack2(__expf(BETA * (s0[0] - 1.f)), __expf(BETA * (s0[1] - 1.f)));
    w0.y = pack2(__expf(BETA * (s0[2] - 1.f)), __expf(BETA * (s0[3] - 1.f)));
    w1.x = pack2(__expf(BETA * (s1[0] - 1.f)), __expf(BETA * (s1[1] - 1.f)));
    w1.y = pack2(__expf(BETA * (s1[2] - 1.f)), __expf(BETA * (s1[3] - 1.f)));
    *(uint2v*)&P_lds[buf][prow + (nh*2 + 0) * 16 + quad * 4] = w0;
    *(uint2v*)&P_lds[buf][prow + (nh*2 + 1) * 16 + quad * 4] = w1;
  };

  // prologue: stage(0); bar; {stage(1); GEMM1(0); exp->P[0]}; bar
  stage(0, 0);
  ktf_load(0);
  __syncthreads();                    // staging(0) drained
  {
    stage(1, 1);
    floatx4 s0 = {}, s1 = {};
    gemm1_half(0, 0, s0, s1);
    gemm1_half(0, 8, s0, s1);
    exp_pw(0, s0, s1);
  }
  __syncthreads();                    // P(0) visible; staging(1) drained

  // steady: region c = {stage(c+2); G2(c)h0; G1(c+1)h0; G2(c)h1; ktf(c+1);
  //                     G1(c+1)h1; exp->P(c+1)}; barrier
#pragma unroll 1
  for (int c = 0; c + 2 < CHUNKS; ++c) {
    const int cur = c & 1, nxt = cur ^ 1;
    stage(c + 2, cur);                         // K_lds[cur] free (read region c-1)
    floatx4 s0 = {}, s1 = {};
    gemm2_half(cur, 0);                        // GEMM2(c) kb2=0
    gemm1_half(nxt, 0, s0, s1);                // GEMM1(c+1) first half
    gemm2_half(cur, 1);                        // GEMM2(c) kb2=1 (ktf(c) consumed)
    ktf_load(c + 1);                           // hoisted: ~500cyc cover to barrier
    gemm1_half(nxt, 8, s0, s1);                // GEMM1(c+1) second half
    exp_pw(nxt, s0, s1);                       // P(c+1) -> P_lds[nxt]
    __syncthreads();
  }
  // tail A: region CHUNKS-2 (no staging)
  {
    const int c = CHUNKS - 2, cur = c & 1, nxt = cur ^ 1;
    floatx4 s0 = {}, s1 = {};
    gemm2_half(cur, 0);
    gemm1_half(nxt, 0, s0, s1);
    gemm2_half(cur, 1);
    ktf_load(CHUNKS - 1);
    gemm1_half(nxt, 8, s0, s1);
    exp_pw(nxt, s0, s1);
    __syncthreads();
  }
  // tail B: GEMM2(CHUNKS-1)
  {
    const int cur = (CHUNKS - 1) & 1;
    gemm2_half(cur, 0);
    gemm2_half(cur, 1);
  }

  // ---- epilogue: out += ALPHA * O (out pre-init to Q; atomics L2-coalesce)
  const int colbase = wave * 64 + l15;
#pragma unroll
  for (int tr = 0; tr < 4; ++tr)
#pragma unroll
    for (int td = 0; td < 4; ++td)
#pragma unroll
      for (int r = 0; r < 4; ++r)
        atomicAdd(out + (size_t)(q0 + tr*16 + quad*4 + r) * D + colbase + td*16,
                  ALPHA * oacc[tr][td][r]);
}

extern "C" void kernel_launch(void* const* d_in, const int* in_sizes, int n_in,
                              void* d_out, int out_size, void* d_ws, size_t ws_size,
                              hipStream_t stream) {
  (void)in_sizes; (void)n_in; (void)out_size; (void)ws_size;
  const float* q = (const float*)d_in[0];
  const float* k = (const float*)d_in[1];
  float* out = (float*)d_out;
  unsigned short* Qn  = (unsigned short*)d_ws;          //  4 MB
  unsigned short* Kn  = Qn + (size_t)NB * D;            // 16 MB
  unsigned short* KnT = Kn + (size_t)NK * D;            // 16 MB  (total 36 MB)

  hipLaunchKernelGGL(norm_qk_kernel, dim3(256 + NB / 4), dim3(256), 0, stream,
                     q, k, out, Qn, Kn, KnT);
  hipLaunchKernelGGL(fused_kernel, dim3((NB / BQ) * NSPLIT), dim3(512), 0, stream,
                     Qn, Kn, KnT, out);
}